// Round 14
// baseline (564.170 us; speedup 1.0000x reference)
//
#include <hip/hip_runtime.h>

#define N_NODES 100000
#define N_EDGES 3200000
#define N_GRAPHS 1000
#define NLAYER 4
#define NB 391           // coarse buckets: dst>>8, 391*256 = 100096 >= N_NODES
#define G1 782           // edge-pass blocks: 782*4096 >= N_EDGES
#define EPB 4096         // edges per block in edge passes
#define PCAP 16384       // bucket_sort perm capacity (mean bucket 8184, sd ~90)

typedef __attribute__((ext_vector_type(8))) short bf16x8;
typedef __attribute__((ext_vector_type(4))) float f32x4;

// round-to-nearest-even f32 -> bf16 (finite inputs)
static __device__ __forceinline__ unsigned f2bf(float f) {
  unsigned u = __float_as_uint(f);
  return (u + 0x7fffu + ((u >> 16) & 1u)) >> 16;
}
static __device__ __forceinline__ float bf2f_lo(unsigned u) {
  return __uint_as_float(u << 16);
}
static __device__ __forceinline__ float bf2f_hi(unsigned u) {
  return __uint_as_float(u & 0xffff0000u);
}

// ---------------------------------------------------------------------------
// h_bf[v][c] = bf16(sum_k x[v][k]*emb_w[k][c] + emb_b[c])
__global__ __launch_bounds__(256) void embed_kernel(
    const float* __restrict__ x, const float* __restrict__ emb_w,
    const float* __restrict__ emb_b, unsigned short* __restrict__ h_bf)
{
  int t = blockIdx.x * 256 + threadIdx.x;
  if (t >= N_NODES * 64) return;
  int c = t & 63, v = t >> 6;
  float4 xv = ((const float4*)x)[v];
  float acc = emb_b[c];
  acc = fmaf(xv.x, emb_w[0 * 64 + c], acc);
  acc = fmaf(xv.y, emb_w[1 * 64 + c], acc);
  acc = fmaf(xv.z, emb_w[2 * 64 + c], acc);
  acc = fmaf(xv.w, emb_w[3 * 64 + c], acc);
  h_bf[t] = (unsigned short)f2bf(acc);
}

// ---------------------------------------------------------------------------
// A: per-block LDS histogram of coarse bucket (dst>>8). No device atomics.
__global__ __launch_bounds__(256) void bhist_kernel(
    const int* __restrict__ ei, int* __restrict__ bhist)
{
  __shared__ unsigned hist[NB];
  for (int i = threadIdx.x; i < NB; i += 256) hist[i] = 0;
  __syncthreads();
  int base = blockIdx.x * EPB;
#pragma unroll
  for (int i = 0; i < 16; ++i) {
    int e = base + i * 256 + threadIdx.x;
    if (e < N_EDGES) atomicAdd(&hist[((unsigned)ei[N_EDGES + e]) >> 8], 1u);
  }
  __syncthreads();
  for (int i = threadIdx.x; i < NB; i += 256)
    bhist[blockIdx.x * NB + i] = (int)hist[i];
}

// B1: per-bucket column exclusive scan over the G1 block rows (in place);
// column total -> tots[b]
__global__ __launch_bounds__(256) void colscan_kernel(
    int* __restrict__ bhist, int* __restrict__ tots)
{
  int b = blockIdx.x;  // bucket
  __shared__ int s[256];
  __shared__ int carry;
  if (threadIdx.x == 0) carry = 0;
  __syncthreads();
  for (int c0 = 0; c0 < G1; c0 += 256) {
    int g = c0 + threadIdx.x;
    int v = (g < G1) ? bhist[g * NB + b] : 0;
    s[threadIdx.x] = v;
    __syncthreads();
    for (int off = 1; off < 256; off <<= 1) {
      int y = (threadIdx.x >= off) ? s[threadIdx.x - off] : 0;
      __syncthreads();
      s[threadIdx.x] += y;
      __syncthreads();
    }
    if (g < G1) bhist[g * NB + b] = carry + s[threadIdx.x] - v;  // exclusive
    __syncthreads();
    if (threadIdx.x == 0) carry += s[255];
    __syncthreads();
  }
  if (threadIdx.x == 0) tots[b] = carry;
}

// B2: exclusive scan of bucket totals -> bucket base offsets bb[0..NB]
__global__ __launch_bounds__(512) void bucketscan_kernel(
    const int* __restrict__ tots, int* __restrict__ bb)
{
  __shared__ int s[512];
  int x = ((int)threadIdx.x < NB) ? tots[threadIdx.x] : 0;
  s[threadIdx.x] = x;
  __syncthreads();
  for (int off = 1; off < 512; off <<= 1) {
    int y = (threadIdx.x >= off) ? s[threadIdx.x - off] : 0;
    __syncthreads();
    s[threadIdx.x] += y;
    __syncthreads();
  }
  if ((int)threadIdx.x < NB) bb[threadIdx.x] = s[threadIdx.x] - x;
  if (threadIdx.x == 0) bb[NB] = N_EDGES;
}

// C: scatter edges into coarse buckets, LDS-staged for coalesced writes.
// tmp record: x = src | ((dst&255)<<17), y = ew bits (exact f32)
__global__ __launch_bounds__(256) void bscatter_kernel(
    const int* __restrict__ ei, const float* __restrict__ ea,
    const int* __restrict__ bhist, const int* __restrict__ bb,
    int2* __restrict__ tmp)
{
  __shared__ unsigned hist[NB];
  __shared__ int lbase[NB];
  __shared__ unsigned cur[NB];
  __shared__ int2 stage[EPB];          // 32 KB
  __shared__ unsigned short bid[EPB];  // 8 KB
  __shared__ int carry;
  __shared__ int sbuf[256];
  int tid = threadIdx.x;
  int base = blockIdx.x * EPB;

  for (int i = tid; i < NB; i += 256) hist[i] = 0;
  if (tid == 0) carry = 0;
  __syncthreads();

#pragma unroll
  for (int i = 0; i < 16; ++i) {
    int e = base + i * 256 + tid;
    if (e < N_EDGES) atomicAdd(&hist[((unsigned)ei[N_EDGES + e]) >> 8], 1u);
  }
  __syncthreads();

  for (int c0 = 0; c0 < NB; c0 += 256) {
    int g = c0 + tid;
    int v = (g < NB) ? (int)hist[g] : 0;
    sbuf[tid] = v;
    __syncthreads();
    for (int off = 1; off < 256; off <<= 1) {
      int y = (tid >= off) ? sbuf[tid - off] : 0;
      __syncthreads();
      sbuf[tid] += y;
      __syncthreads();
    }
    if (g < NB) {
      int ex = carry + sbuf[tid] - v;
      lbase[g] = ex;
      cur[g] = (unsigned)ex;
    }
    __syncthreads();
    if (tid == 0) carry += sbuf[255];
    __syncthreads();
  }

#pragma unroll
  for (int i = 0; i < 16; ++i) {
    int e = base + i * 256 + tid;
    if (e < N_EDGES) {
      int d = ei[N_EDGES + e];
      unsigned bkt = ((unsigned)d) >> 8;
      unsigned lp = atomicAdd(&cur[bkt], 1u);
      stage[lp] = make_int2(ei[e] | ((d & 255) << 17), __float_as_int(ea[e]));
      bid[lp] = (unsigned short)bkt;
    }
  }
  __syncthreads();

  int nE = min(EPB, N_EDGES - base);
  for (int i = tid; i < nE; i += 256) {
    int bkt = (int)bid[i];
    int gpos = bb[bkt] + bhist[blockIdx.x * NB + bkt] + (i - lbase[bkt]);
    tmp[gpos] = stage[i];
  }
}

// D: one block per bucket: 256-bin LDS counting sort (u16 permutation) ->
// contiguous streaming csr write (u32/edge: src 17b | ew*2^15 15b);
// emits row_off and exact fp32 degw.
__global__ __launch_bounds__(256) void bucket_sort_kernel(
    const int* __restrict__ bb, const int2* __restrict__ tmp,
    unsigned* __restrict__ csr, int* __restrict__ row_off, float* __restrict__ degw)
{
  int j = blockIdx.x;
  int b0 = bb[j], b1 = bb[j + 1];
  int nE = b1 - b0;
  __shared__ unsigned hist[256];
  __shared__ float dws[256];
  __shared__ int scanbuf[256];
  __shared__ unsigned cur[256];
  __shared__ unsigned short perm[PCAP];  // 32 KB
  int t = threadIdx.x;
  hist[t] = 0;
  dws[t] = 0.f;
  __syncthreads();
  for (int i = t; i < nE; i += 256) {
    int2 r = tmp[b0 + i];
    int bin = ((unsigned)r.x) >> 17;
    atomicAdd(&hist[bin], 1u);
    atomicAdd(&dws[bin], __int_as_float(r.y));
  }
  __syncthreads();
  int v = (int)hist[t];
  scanbuf[t] = v;
  __syncthreads();
  for (int off = 1; off < 256; off <<= 1) {
    int y = (t >= off) ? scanbuf[t - off] : 0;
    __syncthreads();
    scanbuf[t] += y;
    __syncthreads();
  }
  int myexcl = scanbuf[t] - v;
  cur[t] = (unsigned)myexcl;
  int vnode = (j << 8) + t;
  if (vnode < N_NODES) {
    row_off[vnode] = b0 + myexcl;
    degw[vnode] = dws[t];
  }
  if (j == NB - 1 && t == 0) row_off[N_NODES] = N_EDGES;
  __syncthreads();

  if (nE <= PCAP) {
    for (int i = t; i < nE; i += 256) {
      int2 r = tmp[b0 + i];
      int bin = ((unsigned)r.x) >> 17;
      unsigned p = atomicAdd(&cur[bin], 1u);
      perm[p] = (unsigned short)i;
    }
    __syncthreads();
    for (int q = t; q < nE; q += 256) {
      int2 r = tmp[b0 + (int)perm[q]];
      unsigned q15 = (unsigned)(__int_as_float(r.y) * 32768.0f);  // ew in [0,1)
      csr[b0 + q] = ((unsigned)r.x & 0x1FFFFu) | (q15 << 17);
    }
  } else {
    for (int i = t; i < nE; i += 256) {
      int2 r = tmp[b0 + i];
      int bin = ((unsigned)r.x) >> 17;
      unsigned p = atomicAdd(&cur[bin], 1u);
      unsigned q15 = (unsigned)(__int_as_float(r.y) * 32768.0f);
      csr[b0 + (int)p] = ((unsigned)r.x & 0x1FFFFu) | (q15 << 17);
    }
  }
}

// ---------------------------------------------------------------------------
// MFMA matvec: 128 nodes/block (2 row-tiles/wave), grid = 782 (~3 blocks/CU).
//   a_bf  = bf16(h@W1 + b1)
//   cc_bf = bf16(b3 + h@W3 - deg_w*(h@W2))
__global__ __launch_bounds__(256) void matvec3_mfma_kernel(
    const unsigned short* __restrict__ h_bf,
    const float* __restrict__ w1, const float* __restrict__ b1,
    const float* __restrict__ w2,
    const float* __restrict__ w3, const float* __restrict__ b3,
    const float* __restrict__ degw,
    unsigned short* __restrict__ a_bf, unsigned short* __restrict__ cc_bf)
{
  __shared__ unsigned wfrag[6144];  // [m][c][t][lane][j2] = 24 KB
  int tid = threadIdx.x;
  {
    // 96 (m,k-pair) combos; 4 per 256-thread sweep; lanes sweep n (coalesced)
    int n = tid & 63;
    int gofs = tid >> 6;
    for (int it = 0; it < 24; ++it) {
      int g = it * 4 + gofs;         // 0..95
      int m = g >> 5;                // 0..2 (0=W2, 1=W3, 2=W1)
      int kp = g & 31;               // k-pair index
      int k = kp * 2;                // even k
      const float* W = (m == 0) ? w2 : (m == 1) ? w3 : w1;
      unsigned lo = f2bf(W[k * 64 + n]);
      unsigned hi = f2bf(W[(k + 1) * 64 + n]);
      int c = k >> 5;
      int kk = k & 31;
      int lane = ((kk >> 3) << 4) | (n & 15);
      int j2 = (kk & 7) >> 1;
      int t = n >> 4;
      wfrag[(((m * 2 + c) * 4 + t) << 8) | (lane << 2) | j2] = lo | (hi << 16);
    }
  }
  __syncthreads();

  int wave = tid >> 6;
  int lane = tid & 63;
  int quad = lane >> 4;
  int col = lane & 15;

#pragma unroll
  for (int tt = 0; tt < 2; ++tt) {
    int nb = blockIdx.x * 128 + wave * 32 + tt * 16;  // node base of 16 rows
    int arow = nb + col;
    if (arow >= N_NODES) arow = N_NODES - 1;
    const bf16x8* ap = (const bf16x8*)(h_bf + (size_t)arow * 64 + quad * 8);
    bf16x8 af0 = ap[0];  // k = quad*8 + j
    bf16x8 af1 = ap[4];  // k = 32 + quad*8 + j

    float dwr[4];
#pragma unroll
    for (int r = 0; r < 4; ++r) {
      int row = nb + quad * 4 + r;
      dwr[r] = degw[row < N_NODES ? row : 0];
    }

#pragma unroll
    for (int t = 0; t < 4; ++t) {
      const bf16x8* b20 = (const bf16x8*)&wfrag[((0 * 4 + t) << 8) + lane * 4];
      const bf16x8* b21 = (const bf16x8*)&wfrag[((1 * 4 + t) << 8) + lane * 4];
      const bf16x8* b30 = (const bf16x8*)&wfrag[((2 * 4 + t) << 8) + lane * 4];
      const bf16x8* b31 = (const bf16x8*)&wfrag[((3 * 4 + t) << 8) + lane * 4];
      const bf16x8* b10 = (const bf16x8*)&wfrag[((4 * 4 + t) << 8) + lane * 4];
      const bf16x8* b11 = (const bf16x8*)&wfrag[((5 * 4 + t) << 8) + lane * 4];

      f32x4 z = {0.f, 0.f, 0.f, 0.f};
      f32x4 acc2 = __builtin_amdgcn_mfma_f32_16x16x32_bf16(af0, *b20, z, 0, 0, 0);
      acc2 = __builtin_amdgcn_mfma_f32_16x16x32_bf16(af1, *b21, acc2, 0, 0, 0);
      f32x4 cc;
#pragma unroll
      for (int r = 0; r < 4; ++r) cc[r] = -dwr[r] * acc2[r];
      cc = __builtin_amdgcn_mfma_f32_16x16x32_bf16(af0, *b30, cc, 0, 0, 0);
      cc = __builtin_amdgcn_mfma_f32_16x16x32_bf16(af1, *b31, cc, 0, 0, 0);
      float bb3 = b3[t * 16 + col];
#pragma unroll
      for (int r = 0; r < 4; ++r) {
        int row = nb + quad * 4 + r;
        if (row < N_NODES)
          cc_bf[(size_t)row * 64 + t * 16 + col] = (unsigned short)f2bf(cc[r] + bb3);
      }

      float bb1 = b1[t * 16 + col];
      f32x4 a1 = {bb1, bb1, bb1, bb1};
      a1 = __builtin_amdgcn_mfma_f32_16x16x32_bf16(af0, *b10, a1, 0, 0, 0);
      a1 = __builtin_amdgcn_mfma_f32_16x16x32_bf16(af1, *b11, a1, 0, 0, 0);
#pragma unroll
      for (int r = 0; r < 4; ++r) {
        int row = nb + quad * 4 + r;
        if (row < N_NODES)
          a_bf[(size_t)row * 64 + t * 16 + col] = (unsigned short)f2bf(a1[r]);
      }
    }
  }
}

// ---------------------------------------------------------------------------
// h_new[v] = relu(cc[v] + sum_{e in CSR(v)} ew_e * a[src_e])
// 8 nodes/wave, 8 lanes per node (uint4 = 16 B/lane, 8 channels each);
// chunk=16 with two record regs -> up to 16 outstanding gathers.
__global__ __launch_bounds__(256) void agg_kernel(
    const uint4* __restrict__ a4, const uint4* __restrict__ cc4,
    const int* __restrict__ row_off, const unsigned* __restrict__ csr,
    float4* __restrict__ h4, uint4* __restrict__ hbf4, int write_h)
{
  int wave = (blockIdx.x * 256 + threadIdx.x) >> 6;
  int lane = threadIdx.x & 63;
  int sg = lane >> 3;   // subgroup 0..7
  int li = lane & 7;    // lane in subgroup; channels li*8 .. li*8+7
  int v = wave * 8 + sg;
  bool valid = v < N_NODES;
  int vc = valid ? v : N_NODES - 1;
  int base = row_off[vc];
  int ecnt = valid ? (row_off[vc + 1] - base) : 0;
  int emax = ecnt;
  emax = max(emax, __shfl_xor(emax, 8));
  emax = max(emax, __shfl_xor(emax, 16));
  emax = max(emax, __shfl_xor(emax, 32));

  float acc[8];
  if (valid) {
    uint4 cu = cc4[(size_t)vc * 8 + li];
    acc[0] = bf2f_lo(cu.x); acc[1] = bf2f_hi(cu.x);
    acc[2] = bf2f_lo(cu.y); acc[3] = bf2f_hi(cu.y);
    acc[4] = bf2f_lo(cu.z); acc[5] = bf2f_hi(cu.z);
    acc[6] = bf2f_lo(cu.w); acc[7] = bf2f_hi(cu.w);
  } else {
#pragma unroll
    for (int i = 0; i < 8; ++i) acc[i] = 0.f;
  }

  auto edge_mac = [&](unsigned r) {
    int s = (int)(r & 0x1FFFFu);
    float w = (float)(r >> 17) * (1.0f / 32768.0f);
    uint4 u = a4[(size_t)s * 8 + li];
    acc[0] = fmaf(w, bf2f_lo(u.x), acc[0]);
    acc[1] = fmaf(w, bf2f_hi(u.x), acc[1]);
    acc[2] = fmaf(w, bf2f_lo(u.y), acc[2]);
    acc[3] = fmaf(w, bf2f_hi(u.y), acc[3]);
    acc[4] = fmaf(w, bf2f_lo(u.z), acc[4]);
    acc[5] = fmaf(w, bf2f_hi(u.z), acc[5]);
    acc[6] = fmaf(w, bf2f_lo(u.w), acc[6]);
    acc[7] = fmaf(w, bf2f_hi(u.w), acc[7]);
  };

  int full = emax & ~15;
  int c0 = 0;
  for (; c0 < full; c0 += 16) {
    int ia = c0 + li, ib = c0 + 8 + li;
    unsigned erA = (ia < ecnt) ? csr[base + ia] : 0u;  // pad: src 0, w 0
    unsigned erB = (ib < ecnt) ? csr[base + ib] : 0u;
#pragma unroll
    for (int j = 0; j < 8; ++j) edge_mac((unsigned)__shfl((int)erA, sg * 8 + j));
#pragma unroll
    for (int j = 0; j < 8; ++j) edge_mac((unsigned)__shfl((int)erB, sg * 8 + j));
  }
  int rem = emax - full;
  if (rem > 0) {
    int ia = c0 + li, ib = c0 + 8 + li;
    unsigned erA = (ia < ecnt) ? csr[base + ia] : 0u;
    unsigned erB = (ib < ecnt) ? csr[base + ib] : 0u;
    int ra = min(rem, 8);
    for (int j = 0; j < ra; ++j) edge_mac((unsigned)__shfl((int)erA, sg * 8 + j));
    int rb = rem - 8;
    for (int j = 0; j < rb; ++j) edge_mac((unsigned)__shfl((int)erB, sg * 8 + j));
  }

  if (valid) {
#pragma unroll
    for (int i = 0; i < 8; ++i) acc[i] = fmaxf(acc[i], 0.f);
    if (write_h) {
      float4 lo4 = make_float4(acc[0], acc[1], acc[2], acc[3]);
      float4 hi4 = make_float4(acc[4], acc[5], acc[6], acc[7]);
      h4[(size_t)v * 16 + li * 2] = lo4;
      h4[(size_t)v * 16 + li * 2 + 1] = hi4;
    }
    uint4 p;
    p.x = f2bf(acc[0]) | (f2bf(acc[1]) << 16);
    p.y = f2bf(acc[2]) | (f2bf(acc[3]) << 16);
    p.z = f2bf(acc[4]) | (f2bf(acc[5]) << 16);
    p.w = f2bf(acc[6]) | (f2bf(acc[7]) << 16);
    hbf4[(size_t)v * 8 + li] = p;
  }
}

// ---------------------------------------------------------------------------
// fused mean-pool (sorted batch, binary search) + lin1+relu + lin2, wave/graph
__global__ __launch_bounds__(256) void head_kernel(
    const float* __restrict__ h, const int* __restrict__ batch,
    const float* __restrict__ l1w, const float* __restrict__ l1b,
    const float* __restrict__ l2w, const float* __restrict__ l2b,
    float* __restrict__ out)
{
  int g = (blockIdx.x * 256 + threadIdx.x) >> 6;
  int lane = threadIdx.x & 63;
  if (g >= N_GRAPHS) return;
  int lo = 0, hi = N_NODES;
  while (lo < hi) { int mid = (lo + hi) >> 1; if (batch[mid] < g) lo = mid + 1; else hi = mid; }
  int start = lo;
  hi = N_NODES;
  while (lo < hi) { int mid = (lo + hi) >> 1; if (batch[mid] < g + 1) lo = mid + 1; else hi = mid; }
  int end = lo;

  float sum = 0.f;
  for (int v = start; v < end; ++v) sum += h[(size_t)v * 64 + lane];
  float cntf = (float)(end - start);
  float gx = sum / fmaxf(cntf, 1.f);

  float acc = l1b[lane];
  for (int k = 0; k < 64; ++k) {
    float gxk = __shfl(gx, k);
    acc = fmaf(gxk, l1w[k * 64 + lane], acc);
  }
  float t = fmaxf(acc, 0.f);
  float p0 = t * l2w[lane * 3 + 0];
  float p1 = t * l2w[lane * 3 + 1];
  float p2 = t * l2w[lane * 3 + 2];
  for (int off = 32; off > 0; off >>= 1) {
    p0 += __shfl_down(p0, off);
    p1 += __shfl_down(p1, off);
    p2 += __shfl_down(p2, off);
  }
  if (lane == 0) {
    out[g * 3 + 0] = p0 + l2b[0];
    out[g * 3 + 1] = p1 + l2b[1];
    out[g * 3 + 2] = p2 + l2b[2];
  }
}

// ---------------------------------------------------------------------------
extern "C" void kernel_launch(void* const* d_in, const int* in_sizes, int n_in,
                              void* d_out, int out_size, void* d_ws, size_t ws_size,
                              hipStream_t stream)
{
  (void)in_sizes; (void)n_in; (void)out_size; (void)ws_size;
  const float* x     = (const float*)d_in[0];
  const int*   ei    = (const int*)d_in[1];
  const float* ea    = (const float*)d_in[2];
  const int*   batch = (const int*)d_in[3];
  const float* emb_w = (const float*)d_in[4];
  const float* emb_b = (const float*)d_in[5];
  const float* cw1   = (const float*)d_in[6];
  const float* cb1   = (const float*)d_in[7];
  const float* cw2   = (const float*)d_in[8];
  const float* cw3   = (const float*)d_in[9];
  const float* cb3   = (const float*)d_in[10];
  const float* l1w   = (const float*)d_in[11];
  const float* l1b   = (const float*)d_in[12];
  const float* l2w   = (const float*)d_in[13];
  const float* l2b   = (const float*)d_in[14];
  float* out = (float*)d_out;

  char* wsb = (char*)d_ws;
  size_t off = 0;
  auto alloc = [&](size_t bytes) {
    char* p = wsb + off;
    off = (off + bytes + 255) & ~(size_t)255;
    return p;
  };
  float* h       = (float*)alloc(sizeof(float) * (size_t)N_NODES * 64);    // 25.6 MB
  unsigned short* h_bf = (unsigned short*)alloc(sizeof(short) * (size_t)N_NODES * 64);
  unsigned short* a_bf = (unsigned short*)alloc(sizeof(short) * (size_t)N_NODES * 64);
  unsigned short* cc_bf = (unsigned short*)alloc(sizeof(short) * (size_t)N_NODES * 64);
  unsigned* csr  = (unsigned*)alloc(sizeof(unsigned) * (size_t)N_EDGES);   // 12.8 MB
  int*   row_off = (int*)alloc(sizeof(int) * (N_NODES + 1));
  float* degw    = (float*)alloc(sizeof(float) * N_NODES);
  int*   bhist   = (int*)alloc(sizeof(int) * (size_t)G1 * NB);
  int*   tots    = (int*)alloc(sizeof(int) * NB);
  int*   bb      = (int*)alloc(sizeof(int) * (NB + 1));
  // tmp (25.6 MB int2) aliases h: h fp32 is only written by the LAST agg,
  // long after bucket_sort consumed tmp.
  int2* tmp = (int2*)h;

  embed_kernel<<<(N_NODES * 64 + 255) / 256, 256, 0, stream>>>(x, emb_w, emb_b, h_bf);
  bhist_kernel<<<G1, 256, 0, stream>>>(ei, bhist);
  colscan_kernel<<<NB, 256, 0, stream>>>(bhist, tots);
  bucketscan_kernel<<<1, 512, 0, stream>>>(tots, bb);
  bscatter_kernel<<<G1, 256, 0, stream>>>(ei, ea, bhist, bb, tmp);
  bucket_sort_kernel<<<NB, 256, 0, stream>>>(bb, tmp, csr, row_off, degw);

  int agg_blocks = (N_NODES + 31) / 32;   // 8 nodes/wave, 4 waves/block
  int mv_blocks = (N_NODES + 127) / 128;  // 128 nodes/block -> 782 blocks
  for (int l = 0; l < NLAYER; ++l) {
    matvec3_mfma_kernel<<<mv_blocks, 256, 0, stream>>>(
        h_bf, cw1 + l * 4096, cb1 + l * 64, cw2 + l * 4096, cw3 + l * 4096,
        cb3 + l * 64, degw, a_bf, cc_bf);
    agg_kernel<<<agg_blocks, 256, 0, stream>>>(
        (const uint4*)a_bf, (const uint4*)cc_bf, row_off, csr, (float4*)h,
        (uint4*)h_bf, (l == NLAYER - 1) ? 1 : 0);
  }

  head_kernel<<<(N_GRAPHS * 64 + 255) / 256, 256, 0, stream>>>(
      h, batch, l1w, l1b, l2w, l2b, out);
}

// Round 15
// 531.095 us; speedup vs baseline: 1.0623x; 1.0623x over previous
//
#include <hip/hip_runtime.h>

#define N_NODES 100000
#define N_EDGES 3200000
#define N_GRAPHS 1000
#define NLAYER 4
#define NB 391           // coarse buckets: dst>>8, 391*256 = 100096 >= N_NODES
#define G1 782           // edge-pass blocks: 782*4096 >= N_EDGES
#define EPB 4096         // edges per block in edge passes
#define PCAP 16384       // bucket_sort perm capacity (mean bucket 8184, sd ~90)

typedef __attribute__((ext_vector_type(8))) short bf16x8;
typedef __attribute__((ext_vector_type(4))) float f32x4;

// round-to-nearest-even f32 -> bf16 (finite inputs)
static __device__ __forceinline__ unsigned f2bf(float f) {
  unsigned u = __float_as_uint(f);
  return (u + 0x7fffu + ((u >> 16) & 1u)) >> 16;
}
static __device__ __forceinline__ float bf2f_lo(unsigned u) {
  return __uint_as_float(u << 16);
}
static __device__ __forceinline__ float bf2f_hi(unsigned u) {
  return __uint_as_float(u & 0xffff0000u);
}

// ---------------------------------------------------------------------------
// h_bf[v][c] = bf16(sum_k x[v][k]*emb_w[k][c] + emb_b[c])
__global__ __launch_bounds__(256) void embed_kernel(
    const float* __restrict__ x, const float* __restrict__ emb_w,
    const float* __restrict__ emb_b, unsigned short* __restrict__ h_bf)
{
  int t = blockIdx.x * 256 + threadIdx.x;
  if (t >= N_NODES * 64) return;
  int c = t & 63, v = t >> 6;
  float4 xv = ((const float4*)x)[v];
  float acc = emb_b[c];
  acc = fmaf(xv.x, emb_w[0 * 64 + c], acc);
  acc = fmaf(xv.y, emb_w[1 * 64 + c], acc);
  acc = fmaf(xv.z, emb_w[2 * 64 + c], acc);
  acc = fmaf(xv.w, emb_w[3 * 64 + c], acc);
  h_bf[t] = (unsigned short)f2bf(acc);
}

// ---------------------------------------------------------------------------
// A: per-block LDS histogram of coarse bucket (dst>>8). No device atomics.
__global__ __launch_bounds__(256) void bhist_kernel(
    const int* __restrict__ ei, int* __restrict__ bhist)
{
  __shared__ unsigned hist[NB];
  for (int i = threadIdx.x; i < NB; i += 256) hist[i] = 0;
  __syncthreads();
  int base = blockIdx.x * EPB;
#pragma unroll
  for (int i = 0; i < 16; ++i) {
    int e = base + i * 256 + threadIdx.x;
    if (e < N_EDGES) atomicAdd(&hist[((unsigned)ei[N_EDGES + e]) >> 8], 1u);
  }
  __syncthreads();
  for (int i = threadIdx.x; i < NB; i += 256)
    bhist[blockIdx.x * NB + i] = (int)hist[i];
}

// B1: per-bucket column exclusive scan over the G1 block rows (in place);
// column total -> tots[b]
__global__ __launch_bounds__(256) void colscan_kernel(
    int* __restrict__ bhist, int* __restrict__ tots)
{
  int b = blockIdx.x;  // bucket
  __shared__ int s[256];
  __shared__ int carry;
  if (threadIdx.x == 0) carry = 0;
  __syncthreads();
  for (int c0 = 0; c0 < G1; c0 += 256) {
    int g = c0 + threadIdx.x;
    int v = (g < G1) ? bhist[g * NB + b] : 0;
    s[threadIdx.x] = v;
    __syncthreads();
    for (int off = 1; off < 256; off <<= 1) {
      int y = (threadIdx.x >= off) ? s[threadIdx.x - off] : 0;
      __syncthreads();
      s[threadIdx.x] += y;
      __syncthreads();
    }
    if (g < G1) bhist[g * NB + b] = carry + s[threadIdx.x] - v;  // exclusive
    __syncthreads();
    if (threadIdx.x == 0) carry += s[255];
    __syncthreads();
  }
  if (threadIdx.x == 0) tots[b] = carry;
}

// B2: exclusive scan of bucket totals -> bucket base offsets bb[0..NB]
__global__ __launch_bounds__(512) void bucketscan_kernel(
    const int* __restrict__ tots, int* __restrict__ bb)
{
  __shared__ int s[512];
  int x = ((int)threadIdx.x < NB) ? tots[threadIdx.x] : 0;
  s[threadIdx.x] = x;
  __syncthreads();
  for (int off = 1; off < 512; off <<= 1) {
    int y = (threadIdx.x >= off) ? s[threadIdx.x - off] : 0;
    __syncthreads();
    s[threadIdx.x] += y;
    __syncthreads();
  }
  if ((int)threadIdx.x < NB) bb[threadIdx.x] = s[threadIdx.x] - x;
  if (threadIdx.x == 0) bb[NB] = N_EDGES;
}

// C: scatter edges into coarse buckets, LDS-staged for coalesced writes.
// tmp record: x = src | ((dst&255)<<17), y = ew bits (exact f32)
__global__ __launch_bounds__(256) void bscatter_kernel(
    const int* __restrict__ ei, const float* __restrict__ ea,
    const int* __restrict__ bhist, const int* __restrict__ bb,
    int2* __restrict__ tmp)
{
  __shared__ unsigned hist[NB];
  __shared__ int lbase[NB];
  __shared__ unsigned cur[NB];
  __shared__ int2 stage[EPB];          // 32 KB
  __shared__ unsigned short bid[EPB];  // 8 KB
  __shared__ int carry;
  __shared__ int sbuf[256];
  int tid = threadIdx.x;
  int base = blockIdx.x * EPB;

  for (int i = tid; i < NB; i += 256) hist[i] = 0;
  if (tid == 0) carry = 0;
  __syncthreads();

#pragma unroll
  for (int i = 0; i < 16; ++i) {
    int e = base + i * 256 + tid;
    if (e < N_EDGES) atomicAdd(&hist[((unsigned)ei[N_EDGES + e]) >> 8], 1u);
  }
  __syncthreads();

  for (int c0 = 0; c0 < NB; c0 += 256) {
    int g = c0 + tid;
    int v = (g < NB) ? (int)hist[g] : 0;
    sbuf[tid] = v;
    __syncthreads();
    for (int off = 1; off < 256; off <<= 1) {
      int y = (tid >= off) ? sbuf[tid - off] : 0;
      __syncthreads();
      sbuf[tid] += y;
      __syncthreads();
    }
    if (g < NB) {
      int ex = carry + sbuf[tid] - v;
      lbase[g] = ex;
      cur[g] = (unsigned)ex;
    }
    __syncthreads();
    if (tid == 0) carry += sbuf[255];
    __syncthreads();
  }

#pragma unroll
  for (int i = 0; i < 16; ++i) {
    int e = base + i * 256 + tid;
    if (e < N_EDGES) {
      int d = ei[N_EDGES + e];
      unsigned bkt = ((unsigned)d) >> 8;
      unsigned lp = atomicAdd(&cur[bkt], 1u);
      stage[lp] = make_int2(ei[e] | ((d & 255) << 17), __float_as_int(ea[e]));
      bid[lp] = (unsigned short)bkt;
    }
  }
  __syncthreads();

  int nE = min(EPB, N_EDGES - base);
  for (int i = tid; i < nE; i += 256) {
    int bkt = (int)bid[i];
    int gpos = bb[bkt] + bhist[blockIdx.x * NB + bkt] + (i - lbase[bkt]);
    tmp[gpos] = stage[i];
  }
}

// D: one block per bucket: 256-bin LDS counting sort (u16 permutation) ->
// contiguous streaming csr write (u32/edge: src 17b | ew*2^15 15b);
// emits row_off and exact fp32 degw.
__global__ __launch_bounds__(256) void bucket_sort_kernel(
    const int* __restrict__ bb, const int2* __restrict__ tmp,
    unsigned* __restrict__ csr, int* __restrict__ row_off, float* __restrict__ degw)
{
  int j = blockIdx.x;
  int b0 = bb[j], b1 = bb[j + 1];
  int nE = b1 - b0;
  __shared__ unsigned hist[256];
  __shared__ float dws[256];
  __shared__ int scanbuf[256];
  __shared__ unsigned cur[256];
  __shared__ unsigned short perm[PCAP];  // 32 KB
  int t = threadIdx.x;
  hist[t] = 0;
  dws[t] = 0.f;
  __syncthreads();
  for (int i = t; i < nE; i += 256) {
    int2 r = tmp[b0 + i];
    int bin = ((unsigned)r.x) >> 17;
    atomicAdd(&hist[bin], 1u);
    atomicAdd(&dws[bin], __int_as_float(r.y));
  }
  __syncthreads();
  int v = (int)hist[t];
  scanbuf[t] = v;
  __syncthreads();
  for (int off = 1; off < 256; off <<= 1) {
    int y = (t >= off) ? scanbuf[t - off] : 0;
    __syncthreads();
    scanbuf[t] += y;
    __syncthreads();
  }
  int myexcl = scanbuf[t] - v;
  cur[t] = (unsigned)myexcl;
  int vnode = (j << 8) + t;
  if (vnode < N_NODES) {
    row_off[vnode] = b0 + myexcl;
    degw[vnode] = dws[t];
  }
  if (j == NB - 1 && t == 0) row_off[N_NODES] = N_EDGES;
  __syncthreads();

  if (nE <= PCAP) {
    for (int i = t; i < nE; i += 256) {
      int2 r = tmp[b0 + i];
      int bin = ((unsigned)r.x) >> 17;
      unsigned p = atomicAdd(&cur[bin], 1u);
      perm[p] = (unsigned short)i;
    }
    __syncthreads();
    for (int q = t; q < nE; q += 256) {
      int2 r = tmp[b0 + (int)perm[q]];
      unsigned q15 = (unsigned)(__int_as_float(r.y) * 32768.0f);  // ew in [0,1)
      csr[b0 + q] = ((unsigned)r.x & 0x1FFFFu) | (q15 << 17);
    }
  } else {
    for (int i = t; i < nE; i += 256) {
      int2 r = tmp[b0 + i];
      int bin = ((unsigned)r.x) >> 17;
      unsigned p = atomicAdd(&cur[bin], 1u);
      unsigned q15 = (unsigned)(__int_as_float(r.y) * 32768.0f);
      csr[b0 + (int)p] = ((unsigned)r.x & 0x1FFFFu) | (q15 << 17);
    }
  }
}

// ---------------------------------------------------------------------------
// One-time weight swizzle: all 4 layers' W2/W3/W1 into MFMA B-fragment
// layout in GLOBAL memory (4 x 24 KB). Same verified mapping as before.
// grid = NLAYER blocks x 256 threads.
__global__ __launch_bounds__(256) void wswz_kernel(
    const float* __restrict__ cw1, const float* __restrict__ cw2,
    const float* __restrict__ cw3, unsigned* __restrict__ wswz)
{
  int l = blockIdx.x;
  const float* w1 = cw1 + l * 4096;
  const float* w2 = cw2 + l * 4096;
  const float* w3 = cw3 + l * 4096;
  unsigned* outp = wswz + l * 6144;
  int tid = threadIdx.x;
  int n = tid & 63;
  int gofs = tid >> 6;
  for (int it = 0; it < 24; ++it) {
    int g = it * 4 + gofs;         // 0..95
    int m = g >> 5;                // 0..2 (0=W2, 1=W3, 2=W1)
    int kp = g & 31;               // k-pair index
    int k = kp * 2;                // even k
    const float* W = (m == 0) ? w2 : (m == 1) ? w3 : w1;
    unsigned lo = f2bf(W[k * 64 + n]);
    unsigned hi = f2bf(W[(k + 1) * 64 + n]);
    int c = k >> 5;
    int kk = k & 31;
    int lane = ((kk >> 3) << 4) | (n & 15);
    int j2 = (kk & 7) >> 1;
    int t = n >> 4;
    outp[(((m * 2 + c) * 4 + t) << 8) | (lane << 2) | j2] = lo | (hi << 16);
  }
}

// ---------------------------------------------------------------------------
// MFMA matvec: one 16-node tile per wave, grid = 6250 waves (1563 blocks).
// No LDS, no barrier: B-fragments loaded directly from the pre-swizzled
// global wswz slice (24 KB, L1-resident; per-fragment load is lane*16B
// coalesced). A-frags from h_bf (verified layout).
//   a_bf  = bf16(h@W1 + b1)
//   cc_bf = bf16(b3 + h@W3 - deg_w*(h@W2))
__global__ __launch_bounds__(256) void matvec3_mfma_kernel(
    const unsigned short* __restrict__ h_bf,
    const unsigned* __restrict__ wz,   // this layer's 6144-word slice
    const float* __restrict__ b1, const float* __restrict__ b3,
    const float* __restrict__ degw,
    unsigned short* __restrict__ a_bf, unsigned short* __restrict__ cc_bf)
{
  int gw = (blockIdx.x * 256 + threadIdx.x) >> 6;  // global wave = tile index
  int lane = threadIdx.x & 63;
  int quad = lane >> 4;
  int col = lane & 15;
  int nb = gw * 16;  // node base of this wave's 16 rows
  if (nb >= N_NODES) return;  // wave-uniform exit

  int arow = nb + col;
  if (arow >= N_NODES) arow = N_NODES - 1;
  const bf16x8* ap = (const bf16x8*)(h_bf + (size_t)arow * 64 + quad * 8);
  bf16x8 af0 = ap[0];  // k = quad*8 + j
  bf16x8 af1 = ap[4];  // k = 32 + quad*8 + j

  float dwr[4];
#pragma unroll
  for (int r = 0; r < 4; ++r) {
    int row = nb + quad * 4 + r;
    dwr[r] = degw[row < N_NODES ? row : 0];
  }

#pragma unroll
  for (int t = 0; t < 4; ++t) {
    const bf16x8* b20 = (const bf16x8*)&wz[((0 * 4 + t) << 8) + lane * 4];
    const bf16x8* b21 = (const bf16x8*)&wz[((1 * 4 + t) << 8) + lane * 4];
    const bf16x8* b30 = (const bf16x8*)&wz[((2 * 4 + t) << 8) + lane * 4];
    const bf16x8* b31 = (const bf16x8*)&wz[((3 * 4 + t) << 8) + lane * 4];
    const bf16x8* b10 = (const bf16x8*)&wz[((4 * 4 + t) << 8) + lane * 4];
    const bf16x8* b11 = (const bf16x8*)&wz[((5 * 4 + t) << 8) + lane * 4];

    f32x4 z = {0.f, 0.f, 0.f, 0.f};
    f32x4 acc2 = __builtin_amdgcn_mfma_f32_16x16x32_bf16(af0, *b20, z, 0, 0, 0);
    acc2 = __builtin_amdgcn_mfma_f32_16x16x32_bf16(af1, *b21, acc2, 0, 0, 0);
    f32x4 cc;
#pragma unroll
    for (int r = 0; r < 4; ++r) cc[r] = -dwr[r] * acc2[r];
    cc = __builtin_amdgcn_mfma_f32_16x16x32_bf16(af0, *b30, cc, 0, 0, 0);
    cc = __builtin_amdgcn_mfma_f32_16x16x32_bf16(af1, *b31, cc, 0, 0, 0);
    float bb3 = b3[t * 16 + col];
#pragma unroll
    for (int r = 0; r < 4; ++r) {
      int row = nb + quad * 4 + r;
      if (row < N_NODES)
        cc_bf[(size_t)row * 64 + t * 16 + col] = (unsigned short)f2bf(cc[r] + bb3);
    }

    float bb1 = b1[t * 16 + col];
    f32x4 a1 = {bb1, bb1, bb1, bb1};
    a1 = __builtin_amdgcn_mfma_f32_16x16x32_bf16(af0, *b10, a1, 0, 0, 0);
    a1 = __builtin_amdgcn_mfma_f32_16x16x32_bf16(af1, *b11, a1, 0, 0, 0);
#pragma unroll
    for (int r = 0; r < 4; ++r) {
      int row = nb + quad * 4 + r;
      if (row < N_NODES)
        a_bf[(size_t)row * 64 + t * 16 + col] = (unsigned short)f2bf(a1[r]);
    }
  }
}

// ---------------------------------------------------------------------------
// h_new[v] = relu(cc[v] + sum_{e in CSR(v)} ew_e * a[src_e])
// 4 nodes/wave, 16 lanes per node; a/cc bf16; csr u32 (src|q15<<17).
// Writes h_bf always; fp32 h only when write_h != 0 (last layer, for head).
__global__ __launch_bounds__(256) void agg_kernel(
    const uint2* __restrict__ a2, const uint2* __restrict__ cc2,
    const int* __restrict__ row_off, const unsigned* __restrict__ csr,
    float4* __restrict__ h4, unsigned short* __restrict__ h_bf, int write_h)
{
  int wave = (blockIdx.x * 256 + threadIdx.x) >> 6;
  int lane = threadIdx.x & 63;
  int sg = lane >> 4;
  int li = lane & 15;
  int v = wave * 4 + sg;
  bool valid = v < N_NODES;
  int vc = valid ? v : N_NODES - 1;
  int base = row_off[vc];
  int ecnt = valid ? (row_off[vc + 1] - base) : 0;
  int emax = ecnt;
  emax = max(emax, __shfl_xor(emax, 16));
  emax = max(emax, __shfl_xor(emax, 32));

  float4 acc = make_float4(0.f, 0.f, 0.f, 0.f);
  if (valid) {
    uint2 cu = cc2[(size_t)vc * 16 + li];
    acc.x = bf2f_lo(cu.x);
    acc.y = bf2f_hi(cu.x);
    acc.z = bf2f_lo(cu.y);
    acc.w = bf2f_hi(cu.y);
  }

  int full = emax & ~15;
  int c0 = 0;
  for (; c0 < full; c0 += 16) {
    int idx = c0 + li;
    unsigned er = (idx < ecnt) ? csr[base + idx] : 0u;  // pad: src 0, w 0
#pragma unroll
    for (int j = 0; j < 16; ++j) {
      unsigned r = (unsigned)__shfl((int)er, sg * 16 + j);
      int s = (int)(r & 0x1FFFFu);
      float w = (float)(r >> 17) * (1.0f / 32768.0f);
      uint2 u = a2[(size_t)s * 16 + li];
      acc.x = fmaf(w, bf2f_lo(u.x), acc.x);
      acc.y = fmaf(w, bf2f_hi(u.x), acc.y);
      acc.z = fmaf(w, bf2f_lo(u.y), acc.z);
      acc.w = fmaf(w, bf2f_hi(u.y), acc.w);
    }
  }
  int rem = emax - full;
  if (rem > 0) {
    int idx = c0 + li;
    unsigned er = (idx < ecnt) ? csr[base + idx] : 0u;
    for (int j = 0; j < rem; ++j) {
      unsigned r = (unsigned)__shfl((int)er, sg * 16 + j);
      int s = (int)(r & 0x1FFFFu);
      float w = (float)(r >> 17) * (1.0f / 32768.0f);
      uint2 u = a2[(size_t)s * 16 + li];
      acc.x = fmaf(w, bf2f_lo(u.x), acc.x);
      acc.y = fmaf(w, bf2f_hi(u.x), acc.y);
      acc.z = fmaf(w, bf2f_lo(u.y), acc.z);
      acc.w = fmaf(w, bf2f_hi(u.y), acc.w);
    }
  }
  if (valid) {
    acc.x = fmaxf(acc.x, 0.f);
    acc.y = fmaxf(acc.y, 0.f);
    acc.z = fmaxf(acc.z, 0.f);
    acc.w = fmaxf(acc.w, 0.f);
    if (write_h) h4[(size_t)v * 16 + li] = acc;
    uint2 p;
    p.x = f2bf(acc.x) | (f2bf(acc.y) << 16);
    p.y = f2bf(acc.z) | (f2bf(acc.w) << 16);
    ((uint2*)h_bf)[(size_t)v * 16 + li] = p;
  }
}

// ---------------------------------------------------------------------------
// fused mean-pool (sorted batch, binary search) + lin1+relu + lin2, wave/graph
__global__ __launch_bounds__(256) void head_kernel(
    const float* __restrict__ h, const int* __restrict__ batch,
    const float* __restrict__ l1w, const float* __restrict__ l1b,
    const float* __restrict__ l2w, const float* __restrict__ l2b,
    float* __restrict__ out)
{
  int g = (blockIdx.x * 256 + threadIdx.x) >> 6;
  int lane = threadIdx.x & 63;
  if (g >= N_GRAPHS) return;
  int lo = 0, hi = N_NODES;
  while (lo < hi) { int mid = (lo + hi) >> 1; if (batch[mid] < g) lo = mid + 1; else hi = mid; }
  int start = lo;
  hi = N_NODES;
  while (lo < hi) { int mid = (lo + hi) >> 1; if (batch[mid] < g + 1) lo = mid + 1; else hi = mid; }
  int end = lo;

  float sum = 0.f;
  for (int v = start; v < end; ++v) sum += h[(size_t)v * 64 + lane];
  float cntf = (float)(end - start);
  float gx = sum / fmaxf(cntf, 1.f);

  float acc = l1b[lane];
  for (int k = 0; k < 64; ++k) {
    float gxk = __shfl(gx, k);
    acc = fmaf(gxk, l1w[k * 64 + lane], acc);
  }
  float t = fmaxf(acc, 0.f);
  float p0 = t * l2w[lane * 3 + 0];
  float p1 = t * l2w[lane * 3 + 1];
  float p2 = t * l2w[lane * 3 + 2];
  for (int off = 32; off > 0; off >>= 1) {
    p0 += __shfl_down(p0, off);
    p1 += __shfl_down(p1, off);
    p2 += __shfl_down(p2, off);
  }
  if (lane == 0) {
    out[g * 3 + 0] = p0 + l2b[0];
    out[g * 3 + 1] = p1 + l2b[1];
    out[g * 3 + 2] = p2 + l2b[2];
  }
}

// ---------------------------------------------------------------------------
extern "C" void kernel_launch(void* const* d_in, const int* in_sizes, int n_in,
                              void* d_out, int out_size, void* d_ws, size_t ws_size,
                              hipStream_t stream)
{
  (void)in_sizes; (void)n_in; (void)out_size; (void)ws_size;
  const float* x     = (const float*)d_in[0];
  const int*   ei    = (const int*)d_in[1];
  const float* ea    = (const float*)d_in[2];
  const int*   batch = (const int*)d_in[3];
  const float* emb_w = (const float*)d_in[4];
  const float* emb_b = (const float*)d_in[5];
  const float* cw1   = (const float*)d_in[6];
  const float* cb1   = (const float*)d_in[7];
  const float* cw2   = (const float*)d_in[8];
  const float* cw3   = (const float*)d_in[9];
  const float* cb3   = (const float*)d_in[10];
  const float* l1w   = (const float*)d_in[11];
  const float* l1b   = (const float*)d_in[12];
  const float* l2w   = (const float*)d_in[13];
  const float* l2b   = (const float*)d_in[14];
  float* out = (float*)d_out;

  char* wsb = (char*)d_ws;
  size_t off = 0;
  auto alloc = [&](size_t bytes) {
    char* p = wsb + off;
    off = (off + bytes + 255) & ~(size_t)255;
    return p;
  };
  float* h       = (float*)alloc(sizeof(float) * (size_t)N_NODES * 64);    // 25.6 MB
  unsigned short* h_bf = (unsigned short*)alloc(sizeof(short) * (size_t)N_NODES * 64);
  unsigned short* a_bf = (unsigned short*)alloc(sizeof(short) * (size_t)N_NODES * 64);
  unsigned short* cc_bf = (unsigned short*)alloc(sizeof(short) * (size_t)N_NODES * 64);
  unsigned* csr  = (unsigned*)alloc(sizeof(unsigned) * (size_t)N_EDGES);   // 12.8 MB
  int*   row_off = (int*)alloc(sizeof(int) * (N_NODES + 1));
  float* degw    = (float*)alloc(sizeof(float) * N_NODES);
  int*   bhist   = (int*)alloc(sizeof(int) * (size_t)G1 * NB);
  int*   tots    = (int*)alloc(sizeof(int) * NB);
  int*   bb      = (int*)alloc(sizeof(int) * (NB + 1));
  unsigned* wswz = (unsigned*)alloc(sizeof(unsigned) * NLAYER * 6144);  // 96 KB
  // tmp (25.6 MB int2) aliases h: h fp32 is only written by the LAST agg,
  // long after bucket_sort consumed tmp.
  int2* tmp = (int2*)h;

  embed_kernel<<<(N_NODES * 64 + 255) / 256, 256, 0, stream>>>(x, emb_w, emb_b, h_bf);
  wswz_kernel<<<NLAYER, 256, 0, stream>>>(cw1, cw2, cw3, wswz);
  bhist_kernel<<<G1, 256, 0, stream>>>(ei, bhist);
  colscan_kernel<<<NB, 256, 0, stream>>>(bhist, tots);
  bucketscan_kernel<<<1, 512, 0, stream>>>(tots, bb);
  bscatter_kernel<<<G1, 256, 0, stream>>>(ei, ea, bhist, bb, tmp);
  bucket_sort_kernel<<<NB, 256, 0, stream>>>(bb, tmp, csr, row_off, degw);

  int agg_blocks = (N_NODES + 15) / 16;   // 4 nodes/wave, 4 waves/block
  int mv_blocks = (N_NODES / 16 + 3) / 4 + 1;  // 6250 tiles, 4 waves/block -> 1563
  for (int l = 0; l < NLAYER; ++l) {
    matvec3_mfma_kernel<<<mv_blocks, 256, 0, stream>>>(
        h_bf, wswz + l * 6144, cb1 + l * 64, cb3 + l * 64, degw, a_bf, cc_bf);
    agg_kernel<<<agg_blocks, 256, 0, stream>>>(
        (const uint2*)a_bf, (const uint2*)cc_bf, row_off, csr, (float4*)h,
        h_bf, (l == NLAYER - 1) ? 1 : 0);
  }

  head_kernel<<<(N_GRAPHS * 64 + 255) / 256, 256, 0, stream>>>(
      h, batch, l1w, l1b, l2w, l2b, out);
}